// Round 2
// baseline (225.984 us; speedup 1.0000x reference)
//
#include <hip/hip_runtime.h>

#define ROWS 4
#define N 4096
#define BATCH 8192
#define PAD_STRIDE 264              // 256 + 8 words: breaks power-of-2 bank stride
#define BUF_WORDS (16 * PAD_STRIDE) // 4224 floats per row buffer

typedef float v4f __attribute__((ext_vector_type(4)));

__global__ __launch_bounds__(256, 3)
void butterfly_kernel(const float* __restrict__ x,
                      const float* __restrict__ tw,
                      float* __restrict__ out) {
    __shared__ float lds[2 * BUF_WORDS];   // 33.8 KB, double-buffered transposes
    const int t   = threadIdx.x;
    const int thi = t >> 4;   // t / 16
    const int tlo = t & 15;   // t % 16
    const int row0 = blockIdx.x * ROWS;

    const float4* tw4 = (const float4*)tw;

    float v[ROWS][16];

    // ---- Load: v[r][a] = x[(row0+r)*N + a*256 + t]  (coalesced dword per a)
    #pragma unroll
    for (int r = 0; r < ROWS; ++r) {
        const float* xr = x + (size_t)(row0 + r) * N + t;
        #pragma unroll
        for (int a = 0; a < 16; ++a)
            v[r][a] = __builtin_nontemporal_load(xr + a * 256);
    }

    // ---- Stage A: layers 0..3 (strides 2048,1024,512,256) — pair dim = a
    #pragma unroll
    for (int l = 0; l < 4; ++l) {
        const int bit = 3 - l;
        const int d   = 1 << bit;
        float4 w[8];
        #pragma unroll
        for (int pc = 0; pc < 8; ++pc)
            w[pc] = tw4[l * 2048 + pc * 256 + t];   // p = pc*256 + t
        #pragma unroll
        for (int r = 0; r < ROWS; ++r) {
            #pragma unroll
            for (int pc = 0; pc < 8; ++pc) {
                const int lo = ((pc >> bit) << (bit + 1)) | (pc & (d - 1));
                const int hi = lo + d;
                const float top = v[r][lo];
                const float bot = v[r][hi];
                v[r][lo] = w[pc].x * top + w[pc].y * bot;
                v[r][hi] = w[pc].z * top + w[pc].w * bot;
            }
        }
    }

    // ---- Transpose A->B: thread t held (b=thi,c=tlo) all-a; becomes (a=thi,c=tlo) all-b
    #pragma unroll
    for (int r = 0; r < ROWS; ++r) {
        float* buf = lds + (r & 1) * BUF_WORDS;
        #pragma unroll
        for (int a = 0; a < 16; ++a)
            buf[a * PAD_STRIDE + t] = v[r][a];      // conflict-free (stride-1)
        __syncthreads();
        #pragma unroll
        for (int b = 0; b < 16; ++b)                // 2-way conflict (free)
            v[r][b] = buf[thi * PAD_STRIDE + b * 16 + tlo];
    }

    // ---- Stage B: layers 4..7 (strides 128,64,32,16) — pair dim = b
    #pragma unroll
    for (int l = 4; l < 8; ++l) {
        const int bit = 3 - (l - 4);
        const int d   = 1 << bit;
        float4 w[8];
        #pragma unroll
        for (int pc = 0; pc < 8; ++pc)
            w[pc] = tw4[l * 2048 + thi * 128 + pc * 16 + tlo]; // p = a*128+pc*16+c
        #pragma unroll
        for (int r = 0; r < ROWS; ++r) {
            #pragma unroll
            for (int pc = 0; pc < 8; ++pc) {
                const int lo = ((pc >> bit) << (bit + 1)) | (pc & (d - 1));
                const int hi = lo + d;
                const float top = v[r][lo];
                const float bot = v[r][hi];
                v[r][lo] = w[pc].x * top + w[pc].y * bot;
                v[r][hi] = w[pc].z * top + w[pc].w * bot;
            }
        }
    }

    // ---- Transpose B->C: thread becomes (a=thi,b=tlo) holding contiguous c
    #pragma unroll
    for (int r = 0; r < ROWS; ++r) {
        float* buf = lds + (r & 1) * BUF_WORDS;
        #pragma unroll
        for (int b = 0; b < 16; ++b)                // 2-way conflict (free)
            buf[thi * PAD_STRIDE + b * 16 + tlo] = v[r][b];
        __syncthreads();
        const float* bp = &lds[(r & 1) * BUF_WORDS + thi * PAD_STRIDE + tlo * 16];
        #pragma unroll
        for (int q = 0; q < 4; ++q) {               // contiguous b128 reads
            v4f c4 = *(const v4f*)(bp + 4 * q);
            v[r][4 * q + 0] = c4.x;
            v[r][4 * q + 1] = c4.y;
            v[r][4 * q + 2] = c4.z;
            v[r][4 * q + 3] = c4.w;
        }
    }

    // ---- Stage C: layers 8..11 (strides 8,4,2,1) — pair dim = c
    #pragma unroll
    for (int l = 8; l < 12; ++l) {
        const int bit = 3 - (l - 8);
        const int d   = 1 << bit;
        float4 w[8];
        #pragma unroll
        for (int pc = 0; pc < 8; ++pc)
            w[pc] = tw4[l * 2048 + thi * 128 + tlo * 8 + pc];  // p = a*128+b*8+pc
        #pragma unroll
        for (int r = 0; r < ROWS; ++r) {
            #pragma unroll
            for (int pc = 0; pc < 8; ++pc) {
                const int lo = ((pc >> bit) << (bit + 1)) | (pc & (d - 1));
                const int hi = lo + d;
                const float top = v[r][lo];
                const float bot = v[r][hi];
                v[r][lo] = w[pc].x * top + w[pc].y * bot;
                v[r][hi] = w[pc].z * top + w[pc].w * bot;
            }
        }
    }

    // ---- Store: thread holds elements [16t, 16t+16) of each row — 4x float4
    #pragma unroll
    for (int r = 0; r < ROWS; ++r) {
        float* orow = out + (size_t)(row0 + r) * N + 16 * t;
        #pragma unroll
        for (int q = 0; q < 4; ++q) {
            v4f s4;
            s4.x = v[r][4 * q + 0];
            s4.y = v[r][4 * q + 1];
            s4.z = v[r][4 * q + 2];
            s4.w = v[r][4 * q + 3];
            __builtin_nontemporal_store(s4, (v4f*)(orow + 4 * q));
        }
    }
}

extern "C" void kernel_launch(void* const* d_in, const int* in_sizes, int n_in,
                              void* d_out, int out_size, void* d_ws, size_t ws_size,
                              hipStream_t stream) {
    const float* x  = (const float*)d_in[0];
    const float* tw = (const float*)d_in[1];
    float* out      = (float*)d_out;
    dim3 grid(BATCH / ROWS);
    dim3 block(256);
    hipLaunchKernelGGL(butterfly_kernel, grid, block, 0, stream, x, tw, out);
}

// Round 3
// 112.939 us; speedup vs baseline: 2.0009x; 2.0009x over previous
//
#include <hip/hip_runtime.h>

#define ROWS 4
#define N 4096
#define BATCH 8192
#define PAD_STRIDE 264              // 256 + 8 words: breaks power-of-2 bank stride
#define BUF_WORDS (16 * PAD_STRIDE) // 4224 floats per row buffer

typedef float v4f __attribute__((ext_vector_type(4)));

__global__ __launch_bounds__(256, 3)
void butterfly_kernel(const float* __restrict__ x,
                      const float* __restrict__ tw,
                      float* __restrict__ out) {
    __shared__ float lds[2 * BUF_WORDS];   // 33.8 KB, double-buffered transposes
    const int t   = threadIdx.x;
    const int thi = t >> 4;   // t / 16
    const int tlo = t & 15;   // t % 16
    const int row0 = blockIdx.x * ROWS;

    const float4* tw4 = (const float4*)tw;

    float v[ROWS][16];

    // ---- Load: v[r][a] = x[(row0+r)*N + a*256 + t]  (coalesced dword per a)
    #pragma unroll
    for (int r = 0; r < ROWS; ++r) {
        const float* xr = x + (size_t)(row0 + r) * N + t;
        #pragma unroll
        for (int a = 0; a < 16; ++a)
            v[r][a] = __builtin_nontemporal_load(xr + a * 256);
    }

    // ---- Stage A: layers 0..3 (strides 2048,1024,512,256) — pair dim = a
    #pragma unroll
    for (int l = 0; l < 4; ++l) {
        const int bit = 3 - l;
        const int d   = 1 << bit;
        float4 w[8];
        #pragma unroll
        for (int pc = 0; pc < 8; ++pc)
            w[pc] = tw4[l * 2048 + pc * 256 + t];   // p = pc*256 + t
        #pragma unroll
        for (int r = 0; r < ROWS; ++r) {
            #pragma unroll
            for (int pc = 0; pc < 8; ++pc) {
                const int lo = ((pc >> bit) << (bit + 1)) | (pc & (d - 1));
                const int hi = lo + d;
                const float top = v[r][lo];
                const float bot = v[r][hi];
                v[r][lo] = w[pc].x * top + w[pc].y * bot;
                v[r][hi] = w[pc].z * top + w[pc].w * bot;
            }
        }
    }

    // ---- Transpose A->B: thread t held (b=thi,c=tlo) all-a; becomes (a=thi,c=tlo) all-b
    #pragma unroll
    for (int r = 0; r < ROWS; ++r) {
        float* buf = lds + (r & 1) * BUF_WORDS;
        #pragma unroll
        for (int a = 0; a < 16; ++a)
            buf[a * PAD_STRIDE + t] = v[r][a];      // conflict-free (stride-1)
        __syncthreads();
        #pragma unroll
        for (int b = 0; b < 16; ++b)                // 2-way conflict (free)
            v[r][b] = buf[thi * PAD_STRIDE + b * 16 + tlo];
    }

    // ---- Stage B: layers 4..7 (strides 128,64,32,16) — pair dim = b
    #pragma unroll
    for (int l = 4; l < 8; ++l) {
        const int bit = 3 - (l - 4);
        const int d   = 1 << bit;
        float4 w[8];
        #pragma unroll
        for (int pc = 0; pc < 8; ++pc)
            w[pc] = tw4[l * 2048 + thi * 128 + pc * 16 + tlo]; // p = a*128+pc*16+c
        #pragma unroll
        for (int r = 0; r < ROWS; ++r) {
            #pragma unroll
            for (int pc = 0; pc < 8; ++pc) {
                const int lo = ((pc >> bit) << (bit + 1)) | (pc & (d - 1));
                const int hi = lo + d;
                const float top = v[r][lo];
                const float bot = v[r][hi];
                v[r][lo] = w[pc].x * top + w[pc].y * bot;
                v[r][hi] = w[pc].z * top + w[pc].w * bot;
            }
        }
    }

    // ---- Transpose B->C: thread becomes (a=thi,b=tlo) holding contiguous c
    #pragma unroll
    for (int r = 0; r < ROWS; ++r) {
        float* buf = lds + (r & 1) * BUF_WORDS;
        #pragma unroll
        for (int b = 0; b < 16; ++b)                // 2-way conflict (free)
            buf[thi * PAD_STRIDE + b * 16 + tlo] = v[r][b];
        __syncthreads();
        const float* bp = &lds[(r & 1) * BUF_WORDS + thi * PAD_STRIDE + tlo * 16];
        #pragma unroll
        for (int q = 0; q < 4; ++q) {               // contiguous b128 reads
            v4f c4 = *(const v4f*)(bp + 4 * q);
            v[r][4 * q + 0] = c4.x;
            v[r][4 * q + 1] = c4.y;
            v[r][4 * q + 2] = c4.z;
            v[r][4 * q + 3] = c4.w;
        }
    }

    // ---- Stage C: layers 8..11 (strides 8,4,2,1) — pair dim = c
    #pragma unroll
    for (int l = 8; l < 12; ++l) {
        const int bit = 3 - (l - 8);
        const int d   = 1 << bit;
        float4 w[8];
        #pragma unroll
        for (int pc = 0; pc < 8; ++pc)
            w[pc] = tw4[l * 2048 + thi * 128 + tlo * 8 + pc];  // p = a*128+b*8+pc
        #pragma unroll
        for (int r = 0; r < ROWS; ++r) {
            #pragma unroll
            for (int pc = 0; pc < 8; ++pc) {
                const int lo = ((pc >> bit) << (bit + 1)) | (pc & (d - 1));
                const int hi = lo + d;
                const float top = v[r][lo];
                const float bot = v[r][hi];
                v[r][lo] = w[pc].x * top + w[pc].y * bot;
                v[r][hi] = w[pc].z * top + w[pc].w * bot;
            }
        }
    }

    // ---- Store: thread holds elements [16t, 16t+16) of each row — 4x float4.
    // NOTE: no nontemporal hint here. Lane addresses within one store instr are
    // 64B-strided (16B per 64B sector); normal write-back lets L2 merge the 8
    // partial writes per 128B line into full-line HBM writebacks. The nt hint
    // caused 2.6x write amplification (340MB vs 134MB, R2 counters).
    #pragma unroll
    for (int r = 0; r < ROWS; ++r) {
        float* orow = out + (size_t)(row0 + r) * N + 16 * t;
        #pragma unroll
        for (int q = 0; q < 4; ++q) {
            v4f s4;
            s4.x = v[r][4 * q + 0];
            s4.y = v[r][4 * q + 1];
            s4.z = v[r][4 * q + 2];
            s4.w = v[r][4 * q + 3];
            *(v4f*)(orow + 4 * q) = s4;
        }
    }
}

extern "C" void kernel_launch(void* const* d_in, const int* in_sizes, int n_in,
                              void* d_out, int out_size, void* d_ws, size_t ws_size,
                              hipStream_t stream) {
    const float* x  = (const float*)d_in[0];
    const float* tw = (const float*)d_in[1];
    float* out      = (float*)d_out;
    dim3 grid(BATCH / ROWS);
    dim3 block(256);
    hipLaunchKernelGGL(butterfly_kernel, grid, block, 0, stream, x, tw, out);
}